// Round 18
// baseline (76.232 us; speedup 1.0000x reference)
//
#include <hip/hip_runtime.h>
#include <math.h>

#define TPB   256
#define SL    16             // per-segment length
#define SEGS  65536          // segments per row
#define TLEN  1048576
#define MOFF  4065           // 65047 / 16
#define ROFF  7              // 65047 % 16
#define TPL   256            // 256-seg tiles per row

typedef float v4f __attribute__((ext_vector_type(4)));

__device__ __forceinline__ float comp(const float4& v, int m) {
    return m == 0 ? v.x : m == 1 ? v.y : m == 2 ? v.z : v.w;
}

__device__ __forceinline__ float ipowf(float base, int e) {
    float r = 1.0f, p = base;
    while (e) { if (e & 1) r *= p; p *= p; e >>= 1; }
    return r;
}

#define LOAD8(P, T, U0,U1,U2,U3, W0,W1,W2,W3)                                 \
    asm volatile(                                                             \
        "global_load_dwordx4 %[u0], %[pa], off\n\t"                           \
        "global_load_dwordx4 %[u1], %[pa], off offset:16\n\t"                 \
        "global_load_dwordx4 %[u2], %[pa], off offset:32\n\t"                 \
        "global_load_dwordx4 %[u3], %[pa], off offset:48\n\t"                 \
        "global_load_dwordx4 %[w0], %[ta], off\n\t"                           \
        "global_load_dwordx4 %[w1], %[ta], off offset:16\n\t"                 \
        "global_load_dwordx4 %[w2], %[ta], off offset:32\n\t"                 \
        "global_load_dwordx4 %[w3], %[ta], off offset:48\n\t"                 \
        "s_waitcnt vmcnt(0)"                                                  \
        : [u0] "=&v"(U0), [u1] "=&v"(U1), [u2] "=&v"(U2), [u3] "=&v"(U3),     \
          [w0] "=&v"(W0), [w1] "=&v"(W1), [w2] "=&v"(W2), [w3] "=&v"(W3)      \
        : [pa] "v"(P), [ta] "v"(T)                                            \
        : "memory")

// Pass 1: one segment/thread (R17 geometry). Stores ONLY the long per-seg
// aggregates (short ones are re-derived by the loss kernel from raw);
// tile aggregates for all 4 planes.
__global__ __launch_bounds__(TPB) void ldr_partials(
    const float* __restrict__ pred, const float* __restrict__ targ,
    float amS, float amL, float Ac16S, float Ac16L,
    float* __restrict__ pBL, float* __restrict__ tA, int rows)
{
    __shared__ float wt[4][4];
    const int bgl = blockIdx.x;
    const int r = bgl >> 8, tile = bgl & 255;
    const int j = threadIdx.x, lane = j & 63, w = j >> 6;
    const int m = tile * 256 + j;
    const size_t base = (size_t)r * TLEN + (size_t)m * SL;
    const float* P = pred + base;
    const float* T = targ + base;

    v4f u0, u1, u2, u3, w0, w1, w2, w3;
    LOAD8(P, T, u0, u1, u2, u3, w0, w1, w2, w3);

    float sp = 0.f, st = 0.f, lp = 0.f, lt = 0.f;
    #define PQ(Q) { sp = fmaf(amS, sp, Q.x); lp = fmaf(amL, lp, Q.x);         \
                    sp = fmaf(amS, sp, Q.y); lp = fmaf(amL, lp, Q.y);         \
                    sp = fmaf(amS, sp, Q.z); lp = fmaf(amL, lp, Q.z);         \
                    sp = fmaf(amS, sp, Q.w); lp = fmaf(amL, lp, Q.w); }
    #define TQ(Q) { st = fmaf(amS, st, Q.x); lt = fmaf(amL, lt, Q.x);         \
                    st = fmaf(amS, st, Q.y); lt = fmaf(amL, lt, Q.y);         \
                    st = fmaf(amS, st, Q.z); lt = fmaf(amL, lt, Q.z);         \
                    st = fmaf(amS, st, Q.w); lt = fmaf(amL, lt, Q.w); }
    PQ(u0) PQ(u1) PQ(u2) PQ(u3)
    TQ(w0) TQ(w1) TQ(w2) TQ(w3)
    #undef PQ
    #undef TQ

    const size_t plane = (size_t)rows * SEGS;
    const size_t idx = (size_t)r * SEGS + m;
    pBL[0 * plane + idx] = lp;
    pBL[1 * plane + idx] = lt;

    const float wgtS = ipowf(Ac16S, 63 - lane);
    const float wgtL = ipowf(Ac16L, 63 - lane);
    float vals[4] = { sp * wgtS, st * wgtS, lp * wgtL, lt * wgtL };
    #pragma unroll
    for (int E = 0; E < 4; ++E) {
        float s = vals[E];
        #pragma unroll
        for (int d = 32; d > 0; d >>= 1) s += __shfl_xor(s, d, 64);
        if (lane == 0) wt[w][E] = s;
    }
    __syncthreads();
    if (j == 0) {
        const float A64S = ipowf(Ac16S, 64), A64L = ipowf(Ac16L, 64);
        #pragma unroll
        for (int E = 0; E < 4; ++E) {
            const float A64 = (E < 2) ? A64S : A64L;
            float t = wt[0][E];
            t = fmaf(A64, t, wt[1][E]);
            t = fmaf(A64, t, wt[2][E]);
            t = fmaf(A64, t, wt[3][E]);
            tA[((size_t)E * rows + r) * TPL + tile] = t;
        }
    }
}

// Pass 2: fused loss. Own-tile raw loaded once (asm batch) and reused for
// (a) re-derived short aggregates -> short carries, (b) short EMA values.
// Tile-prefix carries derived in-block from tA (one plane per wave) —
// replaces the former tile_scan kernel and tC buffer. Long per-seg
// aggregates for tiles bl+15/bl+16 still come from pBL.
__global__ __launch_bounds__(TPB) void ldr_loss(
    const float* __restrict__ pred, const float* __restrict__ targ,
    const float* __restrict__ pBL, const float* __restrict__ tA,
    float amS, float amL, float Ac16S, float Ac16L,
    float AcT_S, float AcT_L,
    float* __restrict__ partial, int rows)
{
    __shared__ float sS[2][4], sL[2][4];
    __shared__ float tcS[2], tcL2[2][2];
    __shared__ float longC[2][512];
    __shared__ float rs[4];
    const int bgl = blockIdx.x;
    const int r = bgl >> 8, bl = bgl & 255;
    const int j = threadIdx.x, lane = j & 63, w = j >> 6;
    const int m = bl * 256 + j;
    const size_t plane = (size_t)rows * SEGS;
    const size_t rbase = (size_t)r * SEGS;
    const float* P = pred + (size_t)r * TLEN;
    const float* T = targ + (size_t)r * TLEN;

    // own-tile raw (reused below for short EMA values)
    const float* Pm = P + (size_t)m * SL;
    const float* Tm = T + (size_t)m * SL;
    v4f ur0, ur1, ur2, ur3, tr0, tr1, tr2, tr3;
    LOAD8(Pm, Tm, ur0, ur1, ur2, ur3, tr0, tr1, tr2, tr3);

    // short per-seg aggregates from raw (same fmaf chain as partials)
    float aggS0 = 0.f, aggS1 = 0.f;
    #define AQ(U, V) { aggS0 = fmaf(amS, aggS0, U.x); aggS1 = fmaf(amS, aggS1, V.x); \
                       aggS0 = fmaf(amS, aggS0, U.y); aggS1 = fmaf(amS, aggS1, V.y); \
                       aggS0 = fmaf(amS, aggS0, U.z); aggS1 = fmaf(amS, aggS1, V.z); \
                       aggS0 = fmaf(amS, aggS0, U.w); aggS1 = fmaf(amS, aggS1, V.w); }
    AQ(ur0, tr0) AQ(ur1, tr1) AQ(ur2, tr2) AQ(ur3, tr3)
    #undef AQ

    // wave scan of short aggregates
    const float A1024S = ipowf(Ac16S, 64);
    const float aLaneS = ipowf(Ac16S, lane);
    float inS0 = aggS0, inS1 = aggS1, Ad = Ac16S;
    #pragma unroll
    for (int d = 1; d < 64; d <<= 1) {
        float p0 = __shfl_up(inS0, d, 64);
        float p1 = __shfl_up(inS1, d, 64);
        if (lane >= d) { inS0 = fmaf(Ad, p0, inS0); inS1 = fmaf(Ad, p1, inS1); }
        Ad *= Ad;
    }
    float exS0 = __shfl_up(inS0, 1, 64), exS1 = __shfl_up(inS1, 1, 64);
    if (lane == 0) { exS0 = 0.f; exS1 = 0.f; }
    if (lane == 63) { sS[0][w] = inS0; sS[1][w] = inS1; }

    // long per-seg aggregates (pBL) for tiles bl+15 / bl+16, wave scan
    const int half = j >> 7;
    const int hh = j & 127;
    const int tsel = (bl + 15 + half) & 255;
    const float Ac32L = Ac16L * Ac16L;
    const float A2048L = ipowf(Ac32L, 64);
    const float aLaneL = ipowf(Ac32L, lane);
    float2 agL0 = *(const float2*)(pBL + 0 * plane + rbase + tsel * 256 + 2 * hh);
    float2 agL1 = *(const float2*)(pBL + 1 * plane + rbase + tsel * 256 + 2 * hh);
    float pa0 = fmaf(Ac16L, agL0.x, agL0.y);
    float pa1 = fmaf(Ac16L, agL1.x, agL1.y);
    float inL0 = pa0, inL1 = pa1;
    Ad = Ac32L;
    #pragma unroll
    for (int d = 1; d < 64; d <<= 1) {
        float p0 = __shfl_up(inL0, d, 64);
        float p1 = __shfl_up(inL1, d, 64);
        if (lane >= d) { inL0 = fmaf(Ad, p0, inL0); inL1 = fmaf(Ad, p1, inL1); }
        Ad *= Ad;
    }
    float exL0 = __shfl_up(inL0, 1, 64), exL1 = __shfl_up(inL1, 1, 64);
    if (lane == 0) { exL0 = 0.f; exL1 = 0.f; }
    if (lane == 63) { sL[0][w] = inL0; sL[1][w] = inL1; }

    // in-block tile-prefix scan: wave w handles tA plane w (replaces tC)
    {
        const float AcT  = (w < 2) ? AcT_S : AcT_L;
        const float AcT4 = (AcT * AcT) * (AcT * AcT);
        const float* Av = tA + ((size_t)w * rows + r) * TPL + lane * 4;
        float v0 = Av[0], v1 = Av[1], v2 = Av[2], v3 = Av[3];
        float B = v0;
        B = fmaf(AcT, B, v1); B = fmaf(AcT, B, v2); B = fmaf(AcT, B, v3);
        float incl = B, Ad2 = AcT4;
        #pragma unroll
        for (int d = 1; d < 64; d <<= 1) {
            float pb = __shfl_up(incl, d, 64);
            if (lane >= d) incl = fmaf(Ad2, pb, incl);
            Ad2 *= Ad2;
        }
        float carry = __shfl_up(incl, 1, 64);
        if (lane == 0) carry = 0.f;
        const float c0 = carry;
        const float c1 = fmaf(AcT, c0, v0);
        const float c2 = fmaf(AcT, c1, v1);
        const float c3 = fmaf(AcT, c2, v2);
        if (w < 2) {
            if (lane == (bl >> 2)) {
                const int s = bl & 3;
                tcS[w] = (s == 0) ? c0 : (s == 1) ? c1 : (s == 2) ? c2 : c3;
            }
        } else {
            const int t0i = (bl + 15) & 255, t1i = (bl + 16) & 255;
            if (lane == (t0i >> 2)) {
                const int s = t0i & 3;
                tcL2[w - 2][0] = (s == 0) ? c0 : (s == 1) ? c1 : (s == 2) ? c2 : c3;
            }
            if (lane == (t1i >> 2)) {
                const int s = t1i & 3;
                tcL2[w - 2][1] = (s == 0) ? c0 : (s == 1) ? c1 : (s == 2) ? c2 : c3;
            }
        }
    }
    __syncthreads();

    // combine short carries
    {
        const float baseS0 = tcS[0];
        const float baseS1 = tcS[1];
        float Wc0 = 0.f, Wc1 = 0.f;
        for (int u = 0; u < w; ++u) {
            Wc0 = fmaf(Wc0, A1024S, sS[0][u]);
            Wc1 = fmaf(Wc1, A1024S, sS[1][u]);
        }
        const float aThS = aLaneS * ipowf(A1024S, w);
        exS0 = fmaf(aThS, baseS0, fmaf(aLaneS, Wc0, exS0));
        exS1 = fmaf(aThS, baseS1, fmaf(aLaneS, Wc1, exS1));
    }
    // combine long carries -> LDS window
    {
        const float baseL0 = tcL2[0][half];
        const float baseL1 = tcL2[1][half];
        const int hw = w & 1, fw = w & 2;
        float Wc0 = hw ? sL[0][fw] : 0.f;
        float Wc1 = hw ? sL[1][fw] : 0.f;
        const float aThL = aLaneL * (hw ? A2048L : 1.f);
        float c00 = fmaf(aThL, baseL0, fmaf(aLaneL, Wc0, exL0));
        float c10 = fmaf(aThL, baseL1, fmaf(aLaneL, Wc1, exL1));
        const int i0 = half * 256 + 2 * hh;
        longC[0][i0] = c00; longC[0][i0 + 1] = fmaf(Ac16L, c00, agL0.x);
        longC[1][i0] = c10; longC[1][i0 + 1] = fmaf(Ac16L, c10, agL1.x);
    }
    __syncthreads();
    const float cSp = exS0, cSt = exS1;
    const float cLp = longC[0][225 + j];
    const float cLt = longC[1][225 + j];

    // short EMA values from the registers loaded up top
    float sp[SL], st[SL];
    {
        float ysp = cSp, yst = cSt;
        #define SQ(U, V, QO)                                                  \
            { ysp = fmaf(amS, ysp, U.x); sp[QO + 0] = ysp;                    \
              yst = fmaf(amS, yst, V.x); st[QO + 0] = yst;                    \
              ysp = fmaf(amS, ysp, U.y); sp[QO + 1] = ysp;                    \
              yst = fmaf(amS, yst, V.y); st[QO + 1] = yst;                    \
              ysp = fmaf(amS, ysp, U.z); sp[QO + 2] = ysp;                    \
              yst = fmaf(amS, yst, V.z); st[QO + 2] = yst;                    \
              ysp = fmaf(amS, ysp, U.w); sp[QO + 3] = ysp;                    \
              yst = fmaf(amS, yst, V.w); st[QO + 3] = yst; }
        SQ(ur0, tr0, 0) SQ(ur1, tr1, 4) SQ(ur2, tr2, 8) SQ(ur3, tr3, 12)
        #undef SQ
    }

    // shifted long streams + loss
    const int a = (m + MOFF) & (SEGS - 1);
    const int bseg = (m + MOFF + 1) & (SEGS - 1);
    float ylp = cLp, ylt = cLt;
    const float4* Ap4 = (const float4*)(P + (size_t)a * SL);
    const float4* At4 = (const float4*)(T + (size_t)a * SL);
    const float4* Bp4 = (const float4*)(P + (size_t)bseg * SL);
    const float4* Bt4 = (const float4*)(T + (size_t)bseg * SL);

    float lsum = 0.f;
    #pragma unroll
    for (int q = 0; q < SL / 4; ++q) {
        float4 u = Ap4[q], v = At4[q];
        #pragma unroll
        for (int mm = 0; mm < 4; ++mm) {
            const int e = 4 * q + mm;
            ylp = fmaf(amL, ylp, comp(u, mm));
            ylt = fmaf(amL, ylt, comp(v, mm));
            if (e >= ROFF) {
                const int i = e - ROFF;
                lsum += fabsf(__logf(__fdividef(sp[i] * ylt, st[i] * ylp)));
            }
        }
    }
    #pragma unroll
    for (int q = 0; q < 2; ++q) {
        float4 u = Bp4[q], v = Bt4[q];
        #pragma unroll
        for (int mm = 0; mm < 4; ++mm) {
            const int e = 4 * q + mm;
            if (e < ROFF) {
                ylp = fmaf(amL, ylp, comp(u, mm));
                ylt = fmaf(amL, ylt, comp(v, mm));
                const int i = e + (SL - ROFF);
                lsum += fabsf(__logf(__fdividef(sp[i] * ylt, st[i] * ylp)));
            }
        }
    }

    #pragma unroll
    for (int d = 32; d > 0; d >>= 1) lsum += __shfl_xor(lsum, d, 64);
    if (lane == 0) rs[w] = lsum;
    __syncthreads();
    if (j == 0) partial[bgl] = rs[0] + rs[1] + rs[2] + rs[3];
}

__global__ void ldr_finalize(const float* __restrict__ partial, int nparts,
                             float* __restrict__ out, double inv_n)
{
    __shared__ double sd[256];
    double s = 0.0;
    for (int i = threadIdx.x; i < nparts; i += 256) s += (double)partial[i];
    sd[threadIdx.x] = s;
    __syncthreads();
    for (int d = 128; d > 0; d >>= 1) {
        if (threadIdx.x < d) sd[threadIdx.x] += sd[threadIdx.x + d];
        __syncthreads();
    }
    if (threadIdx.x == 0) out[0] = (float)(sd[0] * inv_n);
}

extern "C" void kernel_launch(void* const* d_in, const int* in_sizes, int n_in,
                              void* d_out, int out_size, void* d_ws, size_t ws_size,
                              hipStream_t stream)
{
    const float* pred = (const float*)d_in[0];
    const float* targ = (const float*)d_in[1];
    const int n = in_sizes[0];
    const int rows = n / TLEN;   // 16

    const double csd = 1.0 - exp(-2200.0 / (50.0 * 44100.0));
    const double cld = 1.0 - exp(-2200.0 / (3000.0 * 44100.0));
    const double amSd = 1.0 - csd, amLd = 1.0 - cld;
    const float amS = (float)amSd, amL = (float)amLd;
    const float Ac16S = (float)pow(amSd, 16.0);
    const float Ac16L = (float)pow(amLd, 16.0);
    const float AcT_S = (float)pow(amSd, 4096.0);   // per 256-seg tile
    const float AcT_L = (float)pow(amLd, 4096.0);

    // ws: [0,256) reserved; pBL (2*rows*SEGS f = 8.4 MB, long planes only);
    // tA (4*rows*TPL f = 64 KB); partial (4096 f).
    char* wsb = (char*)d_ws;
    float* pBL     = (float*)(wsb + 256);
    float* tA      = pBL + (size_t)2 * rows * SEGS;
    float* partial = tA + (size_t)4 * rows * TPL;

    const int nblocks = rows * TPL;                // 4096

    ldr_partials<<<nblocks, TPB, 0, stream>>>(pred, targ, amS, amL,
                                              Ac16S, Ac16L, pBL, tA, rows);
    ldr_loss<<<nblocks, TPB, 0, stream>>>(pred, targ, pBL, tA, amS, amL,
                                          Ac16S, Ac16L, AcT_S, AcT_L,
                                          partial, rows);

    const double inv_n = 1.0 / ((double)rows * (double)TLEN);
    ldr_finalize<<<1, 256, 0, stream>>>(partial, nblocks, (float*)d_out, inv_n);
}

// Round 19
// 73.919 us; speedup vs baseline: 1.0313x; 1.0313x over previous
//
#include <hip/hip_runtime.h>
#include <math.h>

#define TPB   256
#define SL    16             // per-segment length
#define SEGS  65536          // segments per row
#define TLEN  1048576
#define MOFF  4065           // 65047 / 16
#define ROFF  7              // 65047 % 16
#define TPL   256            // 256-seg tiles per row

typedef float v4f __attribute__((ext_vector_type(4)));

__device__ __forceinline__ float comp(const float4& v, int m) {
    return m == 0 ? v.x : m == 1 ? v.y : m == 2 ? v.z : v.w;
}

__device__ __forceinline__ float ipowf(float base, int e) {
    float r = 1.0f, p = base;
    while (e) { if (e & 1) r *= p; p *= p; e >>= 1; }
    return r;
}

#define LOAD8(P, T, U0,U1,U2,U3, W0,W1,W2,W3)                                 \
    asm volatile(                                                             \
        "global_load_dwordx4 %[u0], %[pa], off\n\t"                           \
        "global_load_dwordx4 %[u1], %[pa], off offset:16\n\t"                 \
        "global_load_dwordx4 %[u2], %[pa], off offset:32\n\t"                 \
        "global_load_dwordx4 %[u3], %[pa], off offset:48\n\t"                 \
        "global_load_dwordx4 %[w0], %[ta], off\n\t"                           \
        "global_load_dwordx4 %[w1], %[ta], off offset:16\n\t"                 \
        "global_load_dwordx4 %[w2], %[ta], off offset:32\n\t"                 \
        "global_load_dwordx4 %[w3], %[ta], off offset:48\n\t"                 \
        "s_waitcnt vmcnt(0)"                                                  \
        : [u0] "=&v"(U0), [u1] "=&v"(U1), [u2] "=&v"(U2), [u3] "=&v"(U3),     \
          [w0] "=&v"(W0), [w1] "=&v"(W1), [w2] "=&v"(W2), [w3] "=&v"(W3)      \
        : [pa] "v"(P), [ta] "v"(T)                                            \
        : "memory")

// Pass 1: one segment/thread. Stores long per-seg aggregates + tile
// aggregates. (R18 verified, unchanged.)
__global__ __launch_bounds__(TPB) void ldr_partials(
    const float* __restrict__ pred, const float* __restrict__ targ,
    float amS, float amL, float Ac16S, float Ac16L,
    float* __restrict__ pBL, float* __restrict__ tA, int rows)
{
    __shared__ float wt[4][4];
    const int bgl = blockIdx.x;
    const int r = bgl >> 8, tile = bgl & 255;
    const int j = threadIdx.x, lane = j & 63, w = j >> 6;
    const int m = tile * 256 + j;
    const size_t base = (size_t)r * TLEN + (size_t)m * SL;
    const float* P = pred + base;
    const float* T = targ + base;

    v4f u0, u1, u2, u3, w0, w1, w2, w3;
    LOAD8(P, T, u0, u1, u2, u3, w0, w1, w2, w3);

    float sp = 0.f, st = 0.f, lp = 0.f, lt = 0.f;
    #define PQ(Q) { sp = fmaf(amS, sp, Q.x); lp = fmaf(amL, lp, Q.x);         \
                    sp = fmaf(amS, sp, Q.y); lp = fmaf(amL, lp, Q.y);         \
                    sp = fmaf(amS, sp, Q.z); lp = fmaf(amL, lp, Q.z);         \
                    sp = fmaf(amS, sp, Q.w); lp = fmaf(amL, lp, Q.w); }
    #define TQ(Q) { st = fmaf(amS, st, Q.x); lt = fmaf(amL, lt, Q.x);         \
                    st = fmaf(amS, st, Q.y); lt = fmaf(amL, lt, Q.y);         \
                    st = fmaf(amS, st, Q.z); lt = fmaf(amL, lt, Q.z);         \
                    st = fmaf(amS, st, Q.w); lt = fmaf(amL, lt, Q.w); }
    PQ(u0) PQ(u1) PQ(u2) PQ(u3)
    TQ(w0) TQ(w1) TQ(w2) TQ(w3)
    #undef PQ
    #undef TQ

    const size_t plane = (size_t)rows * SEGS;
    const size_t idx = (size_t)r * SEGS + m;
    pBL[0 * plane + idx] = lp;
    pBL[1 * plane + idx] = lt;

    const float wgtS = ipowf(Ac16S, 63 - lane);
    const float wgtL = ipowf(Ac16L, 63 - lane);
    float vals[4] = { sp * wgtS, st * wgtS, lp * wgtL, lt * wgtL };
    #pragma unroll
    for (int E = 0; E < 4; ++E) {
        float s = vals[E];
        #pragma unroll
        for (int d = 32; d > 0; d >>= 1) s += __shfl_xor(s, d, 64);
        if (lane == 0) wt[w][E] = s;
    }
    __syncthreads();
    if (j == 0) {
        const float A64S = ipowf(Ac16S, 64), A64L = ipowf(Ac16L, 64);
        #pragma unroll
        for (int E = 0; E < 4; ++E) {
            const float A64 = (E < 2) ? A64S : A64L;
            float t = wt[0][E];
            t = fmaf(A64, t, wt[1][E]);
            t = fmaf(A64, t, wt[2][E]);
            t = fmaf(A64, t, wt[3][E]);
            tA[((size_t)E * rows + r) * TPL + tile] = t;
        }
    }
}

// Pass 2: fused loss (R18 verified) + T1 XCD-chunked blockIdx swizzle:
// block k's shifted tiles (k+15,k+16) are blocks k+15/k+16's own tiles;
// chunking 512 consecutive logical blocks per XCD makes that sharing hit
// the XCD-private L2 instead of crossing to L3. nwg=4096 % 8 == 0 ->
// simple swizzle is bijective; ring wraps (mod 256) stay intra-chunk
// because a 512-chunk holds 2 complete row-rings.
__global__ __launch_bounds__(TPB) void ldr_loss(
    const float* __restrict__ pred, const float* __restrict__ targ,
    const float* __restrict__ pBL, const float* __restrict__ tA,
    float amS, float amL, float Ac16S, float Ac16L,
    float AcT_S, float AcT_L,
    float* __restrict__ partial, int rows)
{
    __shared__ float sS[2][4], sL[2][4];
    __shared__ float tcS[2], tcL2[2][2];
    __shared__ float longC[2][512];
    __shared__ float rs[4];
    const int nwg = rows * TPL;
    const int cpx = nwg >> 3;
    const int bid = blockIdx.x;
    const int bgl = (bid & 7) * cpx + (bid >> 3);   // XCD-chunked swizzle
    const int r = bgl >> 8, bl = bgl & 255;
    const int j = threadIdx.x, lane = j & 63, w = j >> 6;
    const int m = bl * 256 + j;
    const size_t plane = (size_t)rows * SEGS;
    const size_t rbase = (size_t)r * SEGS;
    const float* P = pred + (size_t)r * TLEN;
    const float* T = targ + (size_t)r * TLEN;

    // own-tile raw (reused below for short EMA values)
    const float* Pm = P + (size_t)m * SL;
    const float* Tm = T + (size_t)m * SL;
    v4f ur0, ur1, ur2, ur3, tr0, tr1, tr2, tr3;
    LOAD8(Pm, Tm, ur0, ur1, ur2, ur3, tr0, tr1, tr2, tr3);

    // short per-seg aggregates from raw (same fmaf chain as partials)
    float aggS0 = 0.f, aggS1 = 0.f;
    #define AQ(U, V) { aggS0 = fmaf(amS, aggS0, U.x); aggS1 = fmaf(amS, aggS1, V.x); \
                       aggS0 = fmaf(amS, aggS0, U.y); aggS1 = fmaf(amS, aggS1, V.y); \
                       aggS0 = fmaf(amS, aggS0, U.z); aggS1 = fmaf(amS, aggS1, V.z); \
                       aggS0 = fmaf(amS, aggS0, U.w); aggS1 = fmaf(amS, aggS1, V.w); }
    AQ(ur0, tr0) AQ(ur1, tr1) AQ(ur2, tr2) AQ(ur3, tr3)
    #undef AQ

    // wave scan of short aggregates
    const float A1024S = ipowf(Ac16S, 64);
    const float aLaneS = ipowf(Ac16S, lane);
    float inS0 = aggS0, inS1 = aggS1, Ad = Ac16S;
    #pragma unroll
    for (int d = 1; d < 64; d <<= 1) {
        float p0 = __shfl_up(inS0, d, 64);
        float p1 = __shfl_up(inS1, d, 64);
        if (lane >= d) { inS0 = fmaf(Ad, p0, inS0); inS1 = fmaf(Ad, p1, inS1); }
        Ad *= Ad;
    }
    float exS0 = __shfl_up(inS0, 1, 64), exS1 = __shfl_up(inS1, 1, 64);
    if (lane == 0) { exS0 = 0.f; exS1 = 0.f; }
    if (lane == 63) { sS[0][w] = inS0; sS[1][w] = inS1; }

    // long per-seg aggregates (pBL) for tiles bl+15 / bl+16, wave scan
    const int half = j >> 7;
    const int hh = j & 127;
    const int tsel = (bl + 15 + half) & 255;
    const float Ac32L = Ac16L * Ac16L;
    const float A2048L = ipowf(Ac32L, 64);
    const float aLaneL = ipowf(Ac32L, lane);
    float2 agL0 = *(const float2*)(pBL + 0 * plane + rbase + tsel * 256 + 2 * hh);
    float2 agL1 = *(const float2*)(pBL + 1 * plane + rbase + tsel * 256 + 2 * hh);
    float pa0 = fmaf(Ac16L, agL0.x, agL0.y);
    float pa1 = fmaf(Ac16L, agL1.x, agL1.y);
    float inL0 = pa0, inL1 = pa1;
    Ad = Ac32L;
    #pragma unroll
    for (int d = 1; d < 64; d <<= 1) {
        float p0 = __shfl_up(inL0, d, 64);
        float p1 = __shfl_up(inL1, d, 64);
        if (lane >= d) { inL0 = fmaf(Ad, p0, inL0); inL1 = fmaf(Ad, p1, inL1); }
        Ad *= Ad;
    }
    float exL0 = __shfl_up(inL0, 1, 64), exL1 = __shfl_up(inL1, 1, 64);
    if (lane == 0) { exL0 = 0.f; exL1 = 0.f; }
    if (lane == 63) { sL[0][w] = inL0; sL[1][w] = inL1; }

    // in-block tile-prefix scan: wave w handles tA plane w
    {
        const float AcT  = (w < 2) ? AcT_S : AcT_L;
        const float AcT4 = (AcT * AcT) * (AcT * AcT);
        const float* Av = tA + ((size_t)w * rows + r) * TPL + lane * 4;
        float v0 = Av[0], v1 = Av[1], v2 = Av[2], v3 = Av[3];
        float B = v0;
        B = fmaf(AcT, B, v1); B = fmaf(AcT, B, v2); B = fmaf(AcT, B, v3);
        float incl = B, Ad2 = AcT4;
        #pragma unroll
        for (int d = 1; d < 64; d <<= 1) {
            float pb = __shfl_up(incl, d, 64);
            if (lane >= d) incl = fmaf(Ad2, pb, incl);
            Ad2 *= Ad2;
        }
        float carry = __shfl_up(incl, 1, 64);
        if (lane == 0) carry = 0.f;
        const float c0 = carry;
        const float c1 = fmaf(AcT, c0, v0);
        const float c2 = fmaf(AcT, c1, v1);
        const float c3 = fmaf(AcT, c2, v2);
        if (w < 2) {
            if (lane == (bl >> 2)) {
                const int s = bl & 3;
                tcS[w] = (s == 0) ? c0 : (s == 1) ? c1 : (s == 2) ? c2 : c3;
            }
        } else {
            const int t0i = (bl + 15) & 255, t1i = (bl + 16) & 255;
            if (lane == (t0i >> 2)) {
                const int s = t0i & 3;
                tcL2[w - 2][0] = (s == 0) ? c0 : (s == 1) ? c1 : (s == 2) ? c2 : c3;
            }
            if (lane == (t1i >> 2)) {
                const int s = t1i & 3;
                tcL2[w - 2][1] = (s == 0) ? c0 : (s == 1) ? c1 : (s == 2) ? c2 : c3;
            }
        }
    }
    __syncthreads();

    // combine short carries
    {
        const float baseS0 = tcS[0];
        const float baseS1 = tcS[1];
        float Wc0 = 0.f, Wc1 = 0.f;
        for (int u = 0; u < w; ++u) {
            Wc0 = fmaf(Wc0, A1024S, sS[0][u]);
            Wc1 = fmaf(Wc1, A1024S, sS[1][u]);
        }
        const float aThS = aLaneS * ipowf(A1024S, w);
        exS0 = fmaf(aThS, baseS0, fmaf(aLaneS, Wc0, exS0));
        exS1 = fmaf(aThS, baseS1, fmaf(aLaneS, Wc1, exS1));
    }
    // combine long carries -> LDS window
    {
        const float baseL0 = tcL2[0][half];
        const float baseL1 = tcL2[1][half];
        const int hw = w & 1, fw = w & 2;
        float Wc0 = hw ? sL[0][fw] : 0.f;
        float Wc1 = hw ? sL[1][fw] : 0.f;
        const float aThL = aLaneL * (hw ? A2048L : 1.f);
        float c00 = fmaf(aThL, baseL0, fmaf(aLaneL, Wc0, exL0));
        float c10 = fmaf(aThL, baseL1, fmaf(aLaneL, Wc1, exL1));
        const int i0 = half * 256 + 2 * hh;
        longC[0][i0] = c00; longC[0][i0 + 1] = fmaf(Ac16L, c00, agL0.x);
        longC[1][i0] = c10; longC[1][i0 + 1] = fmaf(Ac16L, c10, agL1.x);
    }
    __syncthreads();
    const float cSp = exS0, cSt = exS1;
    const float cLp = longC[0][225 + j];
    const float cLt = longC[1][225 + j];

    // short EMA values from the registers loaded up top
    float sp[SL], st[SL];
    {
        float ysp = cSp, yst = cSt;
        #define SQ(U, V, QO)                                                  \
            { ysp = fmaf(amS, ysp, U.x); sp[QO + 0] = ysp;                    \
              yst = fmaf(amS, yst, V.x); st[QO + 0] = yst;                    \
              ysp = fmaf(amS, ysp, U.y); sp[QO + 1] = ysp;                    \
              yst = fmaf(amS, yst, V.y); st[QO + 1] = yst;                    \
              ysp = fmaf(amS, ysp, U.z); sp[QO + 2] = ysp;                    \
              yst = fmaf(amS, yst, V.z); st[QO + 2] = yst;                    \
              ysp = fmaf(amS, ysp, U.w); sp[QO + 3] = ysp;                    \
              yst = fmaf(amS, yst, V.w); st[QO + 3] = yst; }
        SQ(ur0, tr0, 0) SQ(ur1, tr1, 4) SQ(ur2, tr2, 8) SQ(ur3, tr3, 12)
        #undef SQ
    }

    // shifted long streams + loss
    const int a = (m + MOFF) & (SEGS - 1);
    const int bseg = (m + MOFF + 1) & (SEGS - 1);
    float ylp = cLp, ylt = cLt;
    const float4* Ap4 = (const float4*)(P + (size_t)a * SL);
    const float4* At4 = (const float4*)(T + (size_t)a * SL);
    const float4* Bp4 = (const float4*)(P + (size_t)bseg * SL);
    const float4* Bt4 = (const float4*)(T + (size_t)bseg * SL);

    float lsum = 0.f;
    #pragma unroll
    for (int q = 0; q < SL / 4; ++q) {
        float4 u = Ap4[q], v = At4[q];
        #pragma unroll
        for (int mm = 0; mm < 4; ++mm) {
            const int e = 4 * q + mm;
            ylp = fmaf(amL, ylp, comp(u, mm));
            ylt = fmaf(amL, ylt, comp(v, mm));
            if (e >= ROFF) {
                const int i = e - ROFF;
                lsum += fabsf(__logf(__fdividef(sp[i] * ylt, st[i] * ylp)));
            }
        }
    }
    #pragma unroll
    for (int q = 0; q < 2; ++q) {
        float4 u = Bp4[q], v = Bt4[q];
        #pragma unroll
        for (int mm = 0; mm < 4; ++mm) {
            const int e = 4 * q + mm;
            if (e < ROFF) {
                ylp = fmaf(amL, ylp, comp(u, mm));
                ylt = fmaf(amL, ylt, comp(v, mm));
                const int i = e + (SL - ROFF);
                lsum += fabsf(__logf(__fdividef(sp[i] * ylt, st[i] * ylp)));
            }
        }
    }

    #pragma unroll
    for (int d = 32; d > 0; d >>= 1) lsum += __shfl_xor(lsum, d, 64);
    if (lane == 0) rs[w] = lsum;
    __syncthreads();
    if (j == 0) partial[bgl] = rs[0] + rs[1] + rs[2] + rs[3];
}

__global__ void ldr_finalize(const float* __restrict__ partial, int nparts,
                             float* __restrict__ out, double inv_n)
{
    __shared__ double sd[256];
    double s = 0.0;
    for (int i = threadIdx.x; i < nparts; i += 256) s += (double)partial[i];
    sd[threadIdx.x] = s;
    __syncthreads();
    for (int d = 128; d > 0; d >>= 1) {
        if (threadIdx.x < d) sd[threadIdx.x] += sd[threadIdx.x + d];
        __syncthreads();
    }
    if (threadIdx.x == 0) out[0] = (float)(sd[0] * inv_n);
}

extern "C" void kernel_launch(void* const* d_in, const int* in_sizes, int n_in,
                              void* d_out, int out_size, void* d_ws, size_t ws_size,
                              hipStream_t stream)
{
    const float* pred = (const float*)d_in[0];
    const float* targ = (const float*)d_in[1];
    const int n = in_sizes[0];
    const int rows = n / TLEN;   // 16

    const double csd = 1.0 - exp(-2200.0 / (50.0 * 44100.0));
    const double cld = 1.0 - exp(-2200.0 / (3000.0 * 44100.0));
    const double amSd = 1.0 - csd, amLd = 1.0 - cld;
    const float amS = (float)amSd, amL = (float)amLd;
    const float Ac16S = (float)pow(amSd, 16.0);
    const float Ac16L = (float)pow(amLd, 16.0);
    const float AcT_S = (float)pow(amSd, 4096.0);   // per 256-seg tile
    const float AcT_L = (float)pow(amLd, 4096.0);

    // ws: [0,256) reserved; pBL (2*rows*SEGS f = 8.4 MB, long planes only);
    // tA (4*rows*TPL f = 64 KB); partial (4096 f).
    char* wsb = (char*)d_ws;
    float* pBL     = (float*)(wsb + 256);
    float* tA      = pBL + (size_t)2 * rows * SEGS;
    float* partial = tA + (size_t)4 * rows * TPL;

    const int nblocks = rows * TPL;                // 4096

    ldr_partials<<<nblocks, TPB, 0, stream>>>(pred, targ, amS, amL,
                                              Ac16S, Ac16L, pBL, tA, rows);
    ldr_loss<<<nblocks, TPB, 0, stream>>>(pred, targ, pBL, tA, amS, amL,
                                          Ac16S, Ac16L, AcT_S, AcT_L,
                                          partial, rows);

    const double inv_n = 1.0 / ((double)rows * (double)TLEN);
    ldr_finalize<<<1, 256, 0, stream>>>(partial, nblocks, (float*)d_out, inv_n);
}